// Round 6
// baseline (854.901 us; speedup 1.0000x reference)
//
#include <hip/hip_runtime.h>
#include <cstdint>
#include <cstddef>

#define BATCH 32768
#define NHID 256
#define KTOT 2048                    // NHID * 8
#define MAT_ELEMS (NHID * KTOT)      // 524288 elements per weight matrix
#define CHUNK_SHORTS (16 * 64 * 8)   // 8192 shorts = 16KB per K-chunk of packed W

typedef __attribute__((ext_vector_type(8))) short short8;
typedef __attribute__((ext_vector_type(4))) float f32x4;
typedef __attribute__((ext_vector_type(4))) int int4v;

__device__ __forceinline__ float fast_tanh(float x) {
    // t = 1 - 2/(e^{2x}+1); monotone, |t|<1, no NaN/Inf for any finite x
    float e = __expf(2.0f * x);
    return 1.0f - 2.0f / (e + 1.0f);
}

__device__ __forceinline__ unsigned short f2bf(float f) {
    union { float f; unsigned u; } v; v.f = f;
    unsigned r = v.u + 0x7fffu + ((v.u >> 16) & 1u);  // RNE (prepack only)
    return (unsigned short)(r >> 16);
}

// B-operand fragment: T0..T7 of tanh(hv) as 8 bf16 (round-half-up + v_perm pack)
__device__ __forceinline__ short8 cheb_frag(float hv) {
    float t = fast_tanh(hv);
    float t2 = t + t;
    unsigned u[8];
    union { float f; unsigned q; } c;
    u[0] = 0x3f800000u;              // T0 = 1.0
    c.f = t; u[1] = c.q;             // T1 = t
    float Tm = 1.0f, Tc = t;
#pragma unroll
    for (int d = 2; d < 8; ++d) {
        float Tn = fmaf(t2, Tc, -Tm);   // T_d = 2t*T_{d-1} - T_{d-2}
        c.f = Tn; u[d] = c.q;
        Tm = Tc; Tc = Tn;
    }
#pragma unroll
    for (int i = 0; i < 8; ++i) u[i] += 0x8000u;   // round-half-up to bf16
    union { int4v i; short8 s; } r;
    r.i.x = (int)__builtin_amdgcn_perm(u[1], u[0], 0x07060302);
    r.i.y = (int)__builtin_amdgcn_perm(u[3], u[2], 0x07060302);
    r.i.z = (int)__builtin_amdgcn_perm(u[5], u[4], 0x07060302);
    r.i.w = (int)__builtin_amdgcn_perm(u[7], u[6], 0x07060302);
    return r.s;
}

// ---------------------------------------------------------------- RFF embed (transposed out)
// hT[j][b] layout: feature-major, batch contiguous.
__global__ __launch_bounds__(256) void kan_rff(
    const float* __restrict__ x, const float* __restrict__ B, float* __restrict__ hT)
{
    int b = blockIdx.x * 256 + threadIdx.x;
    int j = blockIdx.y;   // 0..127
    float x0 = x[b * 3 + 0], x1 = x[b * 3 + 1], x2 = x[b * 3 + 2];
    float z = x0 * B[j] + x1 * B[128 + j] + x2 * B[256 + j];
    float sn, cs;
    __sincosf(z, &sn, &cs);
    hT[(size_t)j * BATCH + b] = cs;
    hT[(size_t)(j + 128) * BATCH + b] = sn;
}

// ------------------------------------------------- weight prepack to bf16 A-frag order
// pw[((kc*16 + nt)*64 + lane)*8 + j] = bf16( W[nt*16 + (lane&15)][kc*32 + (lane>>4)*8 + j] )
__global__ __launch_bounds__(256) void kan_prepack(
    const float* __restrict__ CU, const float* __restrict__ CV,
    const float* __restrict__ Cin, const float* __restrict__ Cout,
    unsigned short* __restrict__ pw)
{
    int mat = blockIdx.y;   // 0=CU 1=CV 2..5=Cin[i] 6..9=Cout[i]
    const float* src;
    if (mat == 0) src = CU;
    else if (mat == 1) src = CV;
    else if (mat < 6) src = Cin + (size_t)(mat - 2) * MAT_ELEMS;
    else src = Cout + (size_t)(mat - 6) * MAT_ELEMS;
    unsigned short* dst = pw + (size_t)mat * MAT_ELEMS;

    int p8 = blockIdx.x * 256 + threadIdx.x;   // 0..65535 (16B groups)
    int l  = p8 & 63;
    int nt = (p8 >> 6) & 15;
    int kc = p8 >> 10;
    int o = nt * 16 + (l & 15);
    int k = kc * 32 + ((l >> 4) << 3);
    const float* s = src + (size_t)o * KTOT + k;
    short8 v;
#pragma unroll
    for (int j = 0; j < 8; ++j) v[j] = (short)f2bf(s[j]);
    *(short8*)(dst + (size_t)p8 * 8) = v;
}

// ---------------------------------------------------------------- fused KAN GEMM
// BARRIER-FREE, LDS-FREE. Operands swapped: A = weights (prepacked frag order,
// global->VGPR streaming), B = Chebyshev basis computed per-lane in registers
// from transposed activations. Y^T[o][b] = sum_k W[o,k] * T(hT)[k,b].
// Wave tile: 64 outs (mf=4, via blockIdx.y out-split) x 64 batch (nf=4).
// Block = 4 waves covering 256 batch; waves fully independent.
// mode 0: out = g; mode 1: out = s*(v + g*(u-v)) + (1-s)*idb  (all transposed)
__global__ __launch_bounds__(256) void kan_gemm(
    const float* __restrict__ actT,
    const unsigned short* __restrict__ pw0,
    const unsigned short* __restrict__ pw1,
    float* out0, float* out1,
    const float* __restrict__ uT, const float* __restrict__ vT,
    const float* idbT, const float* __restrict__ scal,
    int mode)
{
    const int tid = threadIdx.x;
    const int wv = tid >> 6;
    const int lane = tid & 63;
    const int os = blockIdx.y;                    // out-split 0..3 (64 outs)
    const int b0 = blockIdx.x * 256 + wv * 64;    // batch base for this wave

    const unsigned short* pw = blockIdx.z ? pw1 : pw0;
    float* outp = blockIdx.z ? out1 : out0;

    f32x4 acc[4][4];   // [mf][nf]
#pragma unroll
    for (int i = 0; i < 4; ++i)
#pragma unroll
        for (int j = 0; j < 4; ++j)
            acc[i][j] = (f32x4){0.f, 0.f, 0.f, 0.f};

    // A (weights) per-lane pointer, chunk 0, nt = os*4 + mf (mf via +512-short imm)
    const unsigned short* pA = pw + ((size_t)(os * 4) * 64 + lane) * 8;
    // B (basis) source: lane reads hT[kc*4 + (lane>>4)][b0 + nf*16 + (lane&15)]
    const float* pH = actT + (size_t)(lane >> 4) * BATCH + b0 + (lane & 15);

    short8 af[2][4];
    float hv[2][4];
#pragma unroll
    for (int mf = 0; mf < 4; ++mf) af[0][mf] = *(const short8*)(pA + mf * 512);
#pragma unroll
    for (int nf = 0; nf < 4; ++nf) hv[0][nf] = pH[nf * 16];

#pragma unroll 2
    for (int kc = 0; kc < 64; ++kc) {
        const int cur = kc & 1, nxt = cur ^ 1;
        if (kc < 63) {   // register double-buffer prefetch of chunk kc+1
            pA += CHUNK_SHORTS;
            pH += 4 * (size_t)BATCH;
#pragma unroll
            for (int mf = 0; mf < 4; ++mf) af[nxt][mf] = *(const short8*)(pA + mf * 512);
#pragma unroll
            for (int nf = 0; nf < 4; ++nf) hv[nxt][nf] = pH[nf * 16];
        }
#pragma unroll
        for (int nf = 0; nf < 4; ++nf) {
            short8 bfr = cheb_frag(hv[cur][nf]);
#pragma unroll
            for (int mf = 0; mf < 4; ++mf)
                acc[mf][nf] = __builtin_amdgcn_mfma_f32_16x16x32_bf16(
                    af[cur][mf], bfr, acc[mf][nf], 0, 0, 0);
        }
    }

    // --- epilogue: D row (M) = out, col (N) = batch; row=(lane>>4)*4+reg, col=lane&15
    const int col = lane & 15;
    const int rb = (lane >> 4) * 4;
    float s = 0.f;
    if (mode == 1) s = *scal;
#pragma unroll
    for (int mf = 0; mf < 4; ++mf) {
#pragma unroll
        for (int nf = 0; nf < 4; ++nf) {
            int b = b0 + nf * 16 + col;
#pragma unroll
            for (int r = 0; r < 4; ++r) {
                int orow = os * 64 + mf * 16 + rb + r;
                size_t idx = (size_t)orow * BATCH + b;
                float g = acc[mf][nf][r];
                if (mode == 0) {
                    outp[idx] = g;
                } else {
                    // idb may alias outp: same-thread read-then-write per element — safe
                    float uu = uT[idx], vv = vT[idx], id = idbT[idx];
                    outp[idx] = s * (vv + g * (uu - vv)) + (1.0f - s) * id;
                }
            }
        }
    }
}

// ---------------------------------------------------------------- final layer (N_OUT=1)
// One thread per batch element; hT reads coalesced; C_final broadcast from LDS.
__global__ __launch_bounds__(64) void kan_final(
    const float* __restrict__ hT, const float* __restrict__ Cf, float* __restrict__ out)
{
    __shared__ float cf[KTOT];
    const int tid = threadIdx.x;
    for (int i = tid; i < KTOT; i += 64) cf[i] = Cf[i];
    __syncthreads();
    int b = blockIdx.x * 64 + tid;
    float a = 0.f;
#pragma unroll 4
    for (int i = 0; i < NHID; ++i) {
        float t = fast_tanh(hT[(size_t)i * BATCH + b]);
        const float* c = &cf[i * 8];
        float accv = fmaf(c[1], t, c[0]);
        float t2 = t + t, Tm = 1.0f, Tc = t;
#pragma unroll
        for (int d = 2; d < 8; ++d) {
            float Tn = fmaf(t2, Tc, -Tm);
            accv = fmaf(c[d], Tn, accv);
            Tm = Tc; Tc = Tn;
        }
        a += accv;
    }
    out[b] = a;
}

// ---------------------------------------------------------------- launch
extern "C" void kernel_launch(void* const* d_in, const int* in_sizes, int n_in,
                              void* d_out, int out_size, void* d_ws, size_t ws_size,
                              hipStream_t stream)
{
    const float* x      = (const float*)d_in[0];
    const float* Brff   = (const float*)d_in[1];
    const float* CU     = (const float*)d_in[2];
    const float* CV     = (const float*)d_in[3];
    const float* Cin    = (const float*)d_in[4];
    const float* Cout   = (const float*)d_in[5];
    const float* alphas = (const float*)d_in[6];
    const float* betas  = (const float*)d_in[7];
    const float* Cf     = (const float*)d_in[8];
    float* out = (float*)d_out;

    char* ws = (char*)d_ws;
    const size_t PW_BYTES  = (size_t)10 * MAT_ELEMS * sizeof(unsigned short); // 10.5 MB
    const size_t ACT_BYTES = (size_t)BATCH * NHID * sizeof(float);            // 33.5 MB
    unsigned short* pw = (unsigned short*)ws;    // pw FIRST: any tail overrun lands in acts
    float* P = (float*)(ws + PW_BYTES);                  // h ping
    float* Q = (float*)(ws + PW_BYTES + ACT_BYTES);      // h pong / t1
    float* u = (float*)(ws + PW_BYTES + 2 * ACT_BYTES);
    float* v = (float*)(ws + PW_BYTES + 3 * ACT_BYTES);
    // total: 144.6 MB (same proven footprint as R1-R5)

    kan_rff<<<dim3(BATCH / 256, 128), 256, 0, stream>>>(x, Brff, P);
    kan_prepack<<<dim3(256, 10), 256, 0, stream>>>(CU, CV, Cin, Cout, pw);

    // u and v fused via blockIdx.z; out-split via blockIdx.y
    kan_gemm<<<dim3(BATCH / 256, 4, 2), 256, 0, stream>>>(
        P, pw, pw + MAT_ELEMS, u, v, nullptr, nullptr, nullptr, nullptr, 0);

    for (int i = 0; i < 4; ++i) {
        const unsigned short* pwIn  = pw + (size_t)(2 + i) * MAT_ELEMS;
        const unsigned short* pwOut = pw + (size_t)(6 + i) * MAT_ELEMS;
        // t1 = beta*(v + g(h)*(u-v)) + (1-beta)*h        : act=P, out=Q
        kan_gemm<<<dim3(BATCH / 256, 4, 1), 256, 0, stream>>>(
            P, pwIn, nullptr, Q, nullptr, u, v, P, betas + i, 1);
        // h' = alpha*(v + g(t1)*(u-v)) + (1-alpha)*h     : act=Q, idb=P, out=P
        // (idb==out: per-element same-thread read->write, no cross-thread P reads)
        kan_gemm<<<dim3(BATCH / 256, 4, 1), 256, 0, stream>>>(
            Q, pwOut, nullptr, P, nullptr, u, v, P, alphas + i, 1);
    }

    kan_final<<<BATCH / 64, 64, 0, stream>>>(P, Cf, out);
}

// Round 7
// 626.058 us; speedup vs baseline: 1.3655x; 1.3655x over previous
//
#include <hip/hip_runtime.h>
#include <cstdint>
#include <cstddef>

#define BATCH 32768
#define NHID 256
#define KTOT 2048                    // NHID * 8
#define MAT_ELEMS (NHID * KTOT)      // 524288 elements per weight matrix
#define CHUNK_SHORTS (16 * 64 * 8)   // 8192 shorts = 16KB per K-chunk of packed W

typedef __attribute__((ext_vector_type(8))) short short8;
typedef __attribute__((ext_vector_type(4))) float f32x4;
typedef __attribute__((ext_vector_type(4))) int int4v;

__device__ __forceinline__ float fast_tanh(float x) {
    // t = 1 - 2/(e^{2x}+1); monotone, |t|<1, no NaN/Inf for any finite x
    float e = __expf(2.0f * x);
    return 1.0f - 2.0f / (e + 1.0f);
}

__device__ __forceinline__ unsigned short f2bf(float f) {
    union { float f; unsigned u; } v; v.f = f;
    unsigned r = v.u + 0x7fffu + ((v.u >> 16) & 1u);  // RNE (prepack only)
    return (unsigned short)(r >> 16);
}

// lgkm-only barrier (CK idiom): LDS handoff without draining vmcnt —
// in-flight global prefetches (weights, next-phase act) survive the barrier.
__device__ __forceinline__ void block_sync_lds() {
    asm volatile("s_waitcnt lgkmcnt(0)" ::: "memory");
    __builtin_amdgcn_s_barrier();
    asm volatile("" ::: "memory");
}

// T0..T7 of tanh(hv), packed to 8 bf16 in an int4: round-half-up + v_perm pack
__device__ __forceinline__ int4v cheb_pack(float hv) {
    float t = fast_tanh(hv);
    float t2 = t + t;
    unsigned u[8];
    union { float f; unsigned q; } c;
    u[0] = 0x3f800000u;              // T0 = 1.0
    c.f = t; u[1] = c.q;             // T1 = t
    float Tm = 1.0f, Tc = t;
#pragma unroll
    for (int d = 2; d < 8; ++d) {
        float Tn = fmaf(t2, Tc, -Tm);   // T_d = 2t*T_{d-1} - T_{d-2}
        c.f = Tn; u[d] = c.q;
        Tm = Tc; Tc = Tn;
    }
#pragma unroll
    for (int i = 0; i < 8; ++i) u[i] += 0x8000u;   // round-half-up to bf16
    int4v p;
    p.x = (int)__builtin_amdgcn_perm(u[1], u[0], 0x07060302);
    p.y = (int)__builtin_amdgcn_perm(u[3], u[2], 0x07060302);
    p.z = (int)__builtin_amdgcn_perm(u[5], u[4], 0x07060302);
    p.w = (int)__builtin_amdgcn_perm(u[7], u[6], 0x07060302);
    return p;
}

// ---------------------------------------------------------------- RFF embed (transposed out)
// hT[j][b] layout: feature-major, batch contiguous.
__global__ __launch_bounds__(256) void kan_rff(
    const float* __restrict__ x, const float* __restrict__ B, float* __restrict__ hT)
{
    int b = blockIdx.x * 256 + threadIdx.x;
    int j = blockIdx.y;   // 0..127
    float x0 = x[b * 3 + 0], x1 = x[b * 3 + 1], x2 = x[b * 3 + 2];
    float z = x0 * B[j] + x1 * B[128 + j] + x2 * B[256 + j];
    float sn, cs;
    __sincosf(z, &sn, &cs);
    hT[(size_t)j * BATCH + b] = cs;
    hT[(size_t)(j + 128) * BATCH + b] = sn;
}

// ------------------------------------------------- weight prepack to bf16 A-frag order
// pw[((kc*16 + nt)*64 + lane)*8 + j] = bf16( W[nt*16 + (lane&15)][kc*32 + (lane>>4)*8 + j] )
__global__ __launch_bounds__(256) void kan_prepack(
    const float* __restrict__ CU, const float* __restrict__ CV,
    const float* __restrict__ Cin, const float* __restrict__ Cout,
    unsigned short* __restrict__ pw)
{
    int mat = blockIdx.y;   // 0=CU 1=CV 2..5=Cin[i] 6..9=Cout[i]
    const float* src;
    if (mat == 0) src = CU;
    else if (mat == 1) src = CV;
    else if (mat < 6) src = Cin + (size_t)(mat - 2) * MAT_ELEMS;
    else src = Cout + (size_t)(mat - 6) * MAT_ELEMS;
    unsigned short* dst = pw + (size_t)mat * MAT_ELEMS;

    int p8 = blockIdx.x * 256 + threadIdx.x;   // 0..65535 (16B groups)
    int l  = p8 & 63;
    int nt = (p8 >> 6) & 15;
    int kc = p8 >> 10;
    int o = nt * 16 + (l & 15);
    int k = kc * 32 + ((l >> 4) << 3);
    const float* s = src + (size_t)o * KTOT + k;
    short8 v;
#pragma unroll
    for (int j = 0; j < 8; ++j) v[j] = (short)f2bf(s[j]);
    *(short8*)(dst + (size_t)p8 * 8) = v;
}

// ---------------------------------------------------------------- fused KAN GEMM
// Block = 64-batch tile x ALL 256 outs -> basis computed ONCE per (batch,k)
// device-wide. K phased in quarters: phase = 64 feats x 64 batch basis in
// 64KB LDS (16 or 8 chebs/thread), then a barrier-free 16-chunk MFMA run
// (weights global->VGPR prefetched; basis via contiguous ds_read_b128).
// 8 lgkm-only barriers/block; vmcnt prefetches survive them.
// NT=512 (uv): waves 0-3 -> U (pw0/out0), 4-7 -> V (pw1/out1), shared basis.
// NT=256 (res): 4 waves, MODE=1 epilogue: out = s*(v+g*(u-v)) + (1-s)*idb.
template<int NT, int MODE>
__global__ __launch_bounds__(NT, 2) void kan_gemm(
    const float* __restrict__ actT,
    const unsigned short* __restrict__ pw0,
    const unsigned short* __restrict__ pw1,
    float* out0, float* out1,
    const float* __restrict__ uT, const float* __restrict__ vT,
    const float* idbT, const float* __restrict__ scal)
{
    constexpr int ROWS = (NT == 512) ? 8 : 16;   // feat rows per thread per phase
    __shared__ __attribute__((aligned(16))) unsigned short bas[64 * 64 * 8]; // 64KB

    const int tid = threadIdx.x;
    const int wv = tid >> 6, lane = tid & 63;
    const int os = (NT == 512) ? (wv & 3) : wv;   // out-split 0..3 (64 outs)
    const int sel = (NT == 512) ? (wv >> 2) : 0;
    const int b0 = blockIdx.x * 64;

    const unsigned short* pw = sel ? pw1 : pw0;
    float* outp = sel ? out1 : out0;

    f32x4 acc[4][4];   // [mf][nf]
#pragma unroll
    for (int i = 0; i < 4; ++i)
#pragma unroll
        for (int j = 0; j < 4; ++j)
            acc[i][j] = (f32x4){0.f, 0.f, 0.f, 0.f};

    // --- fill role: thread covers batch bb, feats fgrp*ROWS + q (within phase)
    const int bb = tid & 63;
    const int fgrp = tid >> 6;
    const float* actcol = actT + b0 + bb;
    unsigned short* bw = &bas[(size_t)(fgrp * ROWS * 64 + bb) * 8];

    // --- A (weights) per-lane stream base: ((kc*16 + os*4+mf)*64 + lane)*8
    const unsigned short* pA = pw + (size_t)(os * 4 * 64 + lane) * 8;

    float hv[ROWS], hvn[ROWS];
#pragma unroll
    for (int q = 0; q < ROWS; ++q)
        hv[q] = actcol[(size_t)(fgrp * ROWS + q) * BATCH];

    short8 a_cur[4];
#pragma unroll
    for (int mf = 0; mf < 4; ++mf)
        a_cur[mf] = *(const short8*)(pA + mf * 512);
    const unsigned short* pAn = pA + CHUNK_SHORTS;   // next chunk to prefetch

#pragma unroll 1
    for (int phase = 0; phase < 4; ++phase) {
        block_sync_lds();   // all consumers of previous phase done
#pragma unroll
        for (int q = 0; q < ROWS; ++q)
            *(int4v*)(bw + q * 512) = cheb_pack(hv[q]);
        // prefetch next phase's act values (wrap at end: harmless re-read)
        {
            const int pn = (phase + 1) & 3;
            const float* ac = actcol + (size_t)(pn * 64 + fgrp * ROWS) * BATCH;
#pragma unroll
            for (int q = 0; q < ROWS; ++q)
                hvn[q] = ac[(size_t)q * BATCH];
        }
        block_sync_lds();   // fill visible; weight prefetches still in flight
#pragma unroll
        for (int kcl = 0; kcl < 16; ++kcl) {
            short8 a_nxt[4];
#pragma unroll
            for (int mf = 0; mf < 4; ++mf)
                a_nxt[mf] = *(const short8*)(pAn + (size_t)kcl * CHUNK_SHORTS + mf * 512);
            // (after last chunk this overruns into the next matrix / acts: harmless)
#pragma unroll
            for (int nf = 0; nf < 4; ++nf) {
                short8 bfr = *(const short8*)&bas[
                    ((kcl * 4 + (lane >> 4)) * 64 + nf * 16 + (lane & 15)) * 8];
#pragma unroll
                for (int mf = 0; mf < 4; ++mf)
                    acc[mf][nf] = __builtin_amdgcn_mfma_f32_16x16x32_bf16(
                        a_cur[mf], bfr, acc[mf][nf], 0, 0, 0);
            }
#pragma unroll
            for (int mf = 0; mf < 4; ++mf) a_cur[mf] = a_nxt[mf];
        }
        pAn += 16 * (size_t)CHUNK_SHORTS;
#pragma unroll
        for (int q = 0; q < ROWS; ++q) hv[q] = hvn[q];
    }

    // --- epilogue: D row (M) = out, col (N) = batch; row=(lane>>4)*4+reg, col=lane&15
    const int col = lane & 15;
    const int rb = (lane >> 4) * 4;
    float s = 0.f;
    if (MODE == 1) s = *scal;
#pragma unroll
    for (int mf = 0; mf < 4; ++mf) {
#pragma unroll
        for (int nf = 0; nf < 4; ++nf) {
            int b = b0 + nf * 16 + col;
#pragma unroll
            for (int r = 0; r < 4; ++r) {
                int orow = os * 64 + mf * 16 + rb + r;
                size_t idx = (size_t)orow * BATCH + b;
                float g = acc[mf][nf][r];
                if (MODE == 0) {
                    outp[idx] = g;
                } else {
                    // idb may alias outp: same-thread read-then-write — safe
                    float uu = uT[idx], vvv = vT[idx], id = idbT[idx];
                    outp[idx] = s * (vvv + g * (uu - vvv)) + (1.0f - s) * id;
                }
            }
        }
    }
}

// ---------------------------------------------------------------- final layer (N_OUT=1)
// One thread per batch element; hT reads coalesced; C_final broadcast from LDS.
__global__ __launch_bounds__(64) void kan_final(
    const float* __restrict__ hT, const float* __restrict__ Cf, float* __restrict__ out)
{
    __shared__ float cf[KTOT];
    const int tid = threadIdx.x;
    for (int i = tid; i < KTOT; i += 64) cf[i] = Cf[i];
    __syncthreads();
    int b = blockIdx.x * 64 + tid;
    float a = 0.f;
#pragma unroll 4
    for (int i = 0; i < NHID; ++i) {
        float t = fast_tanh(hT[(size_t)i * BATCH + b]);
        const float* c = &cf[i * 8];
        float accv = fmaf(c[1], t, c[0]);
        float t2 = t + t, Tm = 1.0f, Tc = t;
#pragma unroll
        for (int d = 2; d < 8; ++d) {
            float Tn = fmaf(t2, Tc, -Tm);
            accv = fmaf(c[d], Tn, accv);
            Tm = Tc; Tc = Tn;
        }
        a += accv;
    }
    out[b] = a;
}

// ---------------------------------------------------------------- launch
extern "C" void kernel_launch(void* const* d_in, const int* in_sizes, int n_in,
                              void* d_out, int out_size, void* d_ws, size_t ws_size,
                              hipStream_t stream)
{
    const float* x      = (const float*)d_in[0];
    const float* Brff   = (const float*)d_in[1];
    const float* CU     = (const float*)d_in[2];
    const float* CV     = (const float*)d_in[3];
    const float* Cin    = (const float*)d_in[4];
    const float* Cout   = (const float*)d_in[5];
    const float* alphas = (const float*)d_in[6];
    const float* betas  = (const float*)d_in[7];
    const float* Cf     = (const float*)d_in[8];
    float* out = (float*)d_out;

    char* ws = (char*)d_ws;
    const size_t PW_BYTES  = (size_t)10 * MAT_ELEMS * sizeof(unsigned short); // 10.5 MB
    const size_t ACT_BYTES = (size_t)BATCH * NHID * sizeof(float);            // 33.5 MB
    unsigned short* pw = (unsigned short*)ws;    // pw FIRST: tail overrun lands in acts
    float* P = (float*)(ws + PW_BYTES);                  // h ping
    float* Q = (float*)(ws + PW_BYTES + ACT_BYTES);      // h pong / t1
    float* u = (float*)(ws + PW_BYTES + 2 * ACT_BYTES);
    float* v = (float*)(ws + PW_BYTES + 3 * ACT_BYTES);

    kan_rff<<<dim3(BATCH / 256, 128), 256, 0, stream>>>(x, Brff, P);
    kan_prepack<<<dim3(256, 10), 256, 0, stream>>>(CU, CV, Cin, Cout, pw);

    // u and v in ONE dispatch: 8-wave blocks share the basis across U and V
    kan_gemm<512, 0><<<dim3(BATCH / 64), 512, 0, stream>>>(
        P, pw, pw + MAT_ELEMS, u, v, nullptr, nullptr, nullptr, nullptr);

    for (int i = 0; i < 4; ++i) {
        const unsigned short* pwIn  = pw + (size_t)(2 + i) * MAT_ELEMS;
        const unsigned short* pwOut = pw + (size_t)(6 + i) * MAT_ELEMS;
        // t1 = beta*(v + g(h)*(u-v)) + (1-beta)*h        : act=P, out=Q
        kan_gemm<256, 1><<<dim3(BATCH / 64), 256, 0, stream>>>(
            P, pwIn, nullptr, Q, nullptr, u, v, P, betas + i);
        // h' = alpha*(v + g(t1)*(u-v)) + (1-alpha)*h     : act=Q, idb=P, out=P
        kan_gemm<256, 1><<<dim3(BATCH / 64), 256, 0, stream>>>(
            Q, pwOut, nullptr, P, nullptr, u, v, P, alphas + i);
    }

    kan_final<<<BATCH / 64, 64, 0, stream>>>(P, Cf, out);
}